// Round 4
// baseline (905.342 us; speedup 1.0000x reference)
//
#include <hip/hip_runtime.h>

// GCN layer: out = (D^-1/2 (A+I) D^-1/2) X W^T + b
// N=100000, E=1600000, D=64.
//
// Round 4: drop the per-node CSR sort. Round-3 spent ~160us outside the
// 64us gather, largely in bucket_csr (an extra read+sort+write pass over all
// edge records whose only purpose was register accumulation in gather).
// Instead: one block per 128-node bucket holds the 32KB output tile in LDS
// and accumulates UNSORTED bucket edges via ds_add_f32.
//   - lane = feature: x-row load is one coalesced 256B global_load_dword;
//     the LDS atomic hits 32 banks at 2 lanes/bank = conflict-free (m136).
//     (float4-per-16-lane variant would be 8-way conflicted: stride-4 floats
//     cover only 8 banks. Deliberately scalar here.)
//   - binned_scatter EPB 8192->2048: 196 blocks left 1/4 of CUs idle.
//
// Pipeline:
//   A: coarse hist over NBUCK dst-buckets
//   B: scan bucket counts -> boff, gcur
//   C: binned scatter -> grec[bucket] = (src<<7 | dst_low), unsorted
//   D: bucket_dis: per-bucket LDS hist -> dis = rsqrt(deg+1)
//   E: bucket_agg: LDS tile accumulate -> tmp (aliases d_out)
//   F: gemm: in-place tiled fp32 GEMM

#define BSHIFT 7
#define BNODES 128  // nodes per bucket

__global__ void zero_int_kernel(int* __restrict__ p, int n) {
    int i = blockIdx.x * blockDim.x + threadIdx.x;
    if (i < n) p[i] = 0;
}

// --- Phase A: coarse histogram over dst >> 7 ---
__global__ __launch_bounds__(256) void coarse_hist_kernel(const int* __restrict__ dst,
                                                          int* __restrict__ gcnt,
                                                          int e, int nbuck) {
    extern __shared__ int lh[];
    for (int i = threadIdx.x; i < nbuck; i += 256) lh[i] = 0;
    __syncthreads();
    int stride = gridDim.x * 256;
    for (int i = blockIdx.x * 256 + threadIdx.x; i < e; i += stride)
        atomicAdd(&lh[dst[i] >> BSHIFT], 1);
    __syncthreads();
    for (int i = threadIdx.x; i < nbuck; i += 256) {
        int c = lh[i];
        if (c) atomicAdd(&gcnt[i], c);
    }
}

// --- Phase B: single-block scan of bucket counts (nbuck <= 1024) ---
__global__ void scan_kernel(const int* __restrict__ gcnt, int nbuck,
                            int* __restrict__ boff, int* __restrict__ gcur, int e) {
    __shared__ int sm[1024];
    int t = threadIdx.x;
    int v = (t < nbuck) ? gcnt[t] : 0;
    sm[t] = v;
    __syncthreads();
    for (int o = 1; o < 1024; o <<= 1) {
        int add = (t >= o) ? sm[t - o] : 0;
        __syncthreads();
        sm[t] += add;
        __syncthreads();
    }
    if (t < nbuck) {
        int ex = sm[t] - v;
        boff[t] = ex;
        gcur[t] = ex;
    }
    if (t == 0) boff[nbuck] = e;
}

// --- Phase C: binned scatter of packed edge records into bucket regions ---
#define EPB 2048  // edges per block (782 blocks for E=1.6M -> ~3 blocks/CU)
__global__ __launch_bounds__(256) void binned_scatter_kernel(const int* __restrict__ ei,
                                                             int* __restrict__ gcur,
                                                             unsigned int* __restrict__ grec,
                                                             int e, int nbuck) {
    __shared__ unsigned int lrec[EPB];
    __shared__ unsigned short lbk[EPB];
    extern __shared__ int dyn[];
    int* lh = dyn;            // [nbuck] hist, then cursor
    int* lbase = dyn + nbuck; // [nbuck]
    int t = threadIdx.x;
    for (int i = t; i < nbuck; i += 256) lh[i] = 0;
    __syncthreads();
    int e0 = blockIdx.x * EPB;
    for (int i = t; i < EPB; i += 256) {
        int g = e0 + i;
        if (g >= e) break;
        int s = ei[g];
        int d = ei[e + g];
        int b = d >> BSHIFT;
        lrec[i] = ((unsigned int)s << BSHIFT) | (unsigned int)(d & (BNODES - 1));
        lbk[i] = (unsigned short)b;
        atomicAdd(&lh[b], 1);
    }
    __syncthreads();
    for (int b = t; b < nbuck; b += 256) {
        int c = lh[b];
        lbase[b] = c ? atomicAdd(&gcur[b], c) : 0;
        lh[b] = 0;  // reuse as local cursor
    }
    __syncthreads();
    for (int i = t; i < EPB; i += 256) {
        int g = e0 + i;
        if (g >= e) break;
        int b = lbk[i];
        int pos = lbase[b] + atomicAdd(&lh[b], 1);
        grec[pos] = lrec[i];
    }
}

// --- Phase D: per-bucket degree -> dis = rsqrt(deg+1) ---
__global__ __launch_bounds__(256) void bucket_dis_kernel(const unsigned int* __restrict__ grec,
                                                         const int* __restrict__ boff,
                                                         float* __restrict__ dis, int n) {
    __shared__ int lh[BNODES];
    int t = threadIdx.x;
    int b = blockIdx.x;
    int beg = boff[b];
    int end = boff[b + 1];
    if (t < BNODES) lh[t] = 0;
    __syncthreads();
    for (int i = beg + t; i < end; i += 256)
        atomicAdd(&lh[grec[i] & (BNODES - 1)], 1);
    __syncthreads();
    if (t < BNODES) {
        int node = (b << BSHIFT) + t;
        if (node < n) dis[node] = rsqrtf((float)(lh[t] + 1));
    }
}

// --- Phase E: LDS-tile aggregation over unsorted bucket edges ---
__global__ __launch_bounds__(256) void bucket_agg_kernel(const float* __restrict__ x,
                                                         const unsigned int* __restrict__ grec,
                                                         const int* __restrict__ boff,
                                                         const float* __restrict__ dis,
                                                         float* __restrict__ tmp, int n) {
    __shared__ float acc[BNODES * 64];  // node-major, 32 KB
    __shared__ float dl[BNODES];
    int t = threadIdx.x;
    int b = blockIdx.x;
    int beg = boff[b];
    int end = boff[b + 1];
    int node0 = b << BSHIFT;

    if (t < BNODES) {
        int node = node0 + t;
        dl[t] = (node < n) ? dis[node] : 0.f;
    }
    __syncthreads();

    // self-loop init: acc[row] = x[node] * dis[node]
#pragma unroll
    for (int j = 0; j < 8; ++j) {
        int i = t + j * 256;            // float4 index within tile (2048 total)
        int node = node0 + (i >> 4);
        float4 v = {0.f, 0.f, 0.f, 0.f};
        if (node < n) v = ((const float4*)x)[(size_t)node * 16 + (i & 15)];
        float s = dl[i >> 4];
        ((float4*)acc)[i] = make_float4(v.x * s, v.y * s, v.z * s, v.w * s);
    }
    __syncthreads();

    int wave = t >> 6, lane = t & 63;
    for (int base = beg + wave * 64; base < end; base += 256) {
        int k = end - base;
        if (k > 64) k = 64;
        unsigned int rec = 0;
        float dv = 0.f;
        if (lane < k) {
            rec = grec[base + lane];
            dv = dis[rec >> BSHIFT];
        }
#pragma unroll 4
        for (int j = 0; j < k; ++j) {
            unsigned int r = __shfl(rec, j);
            float w = __shfl(dv, j);
            int src = r >> BSHIFT;
            int dlow = r & (BNODES - 1);
            float v = x[(size_t)src * 64 + lane];   // coalesced 256B row
            atomicAdd(&acc[dlow * 64 + lane], v * w);  // ds_add, 2 lanes/bank: free
        }
    }
    __syncthreads();

    // epilogue: tmp[node] = acc[node] * dis[node]
#pragma unroll
    for (int j = 0; j < 8; ++j) {
        int i = t + j * 256;
        int node = node0 + (i >> 4);
        if (node < n) {
            float4 v = ((const float4*)acc)[i];
            float s = dl[i >> 4];
            ((float4*)tmp)[(size_t)node * 16 + (i & 15)] =
                make_float4(v.x * s, v.y * s, v.z * s, v.w * s);
        }
    }
}

// --- In-place GEMM: out[m,o] = b[o] + sum_k A[m,k]*W[o,k]; A aliases out ---
__global__ __launch_bounds__(256) void gemm_kernel(const float* A,
                                                   const float* __restrict__ W,
                                                   const float* __restrict__ b,
                                                   float* out, int n) {
    __shared__ float At[64 * 68];
    __shared__ float Wt[64 * 64];
    int t = threadIdx.x;
    int m0 = blockIdx.x * 64;

#pragma unroll
    for (int j = 0; j < 16; ++j) {
        int idx = t + j * 256;
        int o = idx >> 6, k = idx & 63;
        Wt[k * 64 + o] = W[idx];
    }
#pragma unroll
    for (int j = 0; j < 16; ++j) {
        int idx = t + j * 256;
        int m = idx >> 6, k = idx & 63;
        int gm = m0 + m;
        At[k * 68 + m] = (gm < n) ? A[(size_t)gm * 64 + k] : 0.f;
    }
    __syncthreads();

    int tx = t & 15, ty = t >> 4;
    float acc[4][4];
#pragma unroll
    for (int i = 0; i < 4; ++i)
#pragma unroll
        for (int j = 0; j < 4; ++j) acc[i][j] = 0.f;

#pragma unroll 8
    for (int k = 0; k < 64; ++k) {
        float4 a = *(const float4*)&At[k * 68 + ty * 4];
        float4 w = *(const float4*)&Wt[k * 64 + tx * 4];
        float av[4] = {a.x, a.y, a.z, a.w};
        float wv[4] = {w.x, w.y, w.z, w.w};
#pragma unroll
        for (int i = 0; i < 4; ++i)
#pragma unroll
            for (int j = 0; j < 4; ++j) acc[i][j] += av[i] * wv[j];
    }

    float4 bb = ((const float4*)b)[tx];
    float bv[4] = {bb.x, bb.y, bb.z, bb.w};
#pragma unroll
    for (int i = 0; i < 4; ++i) {
        int gm = m0 + ty * 4 + i;
        if (gm < n) {
            float4 o;
            o.x = acc[i][0] + bv[0];
            o.y = acc[i][1] + bv[1];
            o.z = acc[i][2] + bv[2];
            o.w = acc[i][3] + bv[3];
            ((float4*)out)[(size_t)gm * 16 + tx] = o;
        }
    }
}

extern "C" void kernel_launch(void* const* d_in, const int* in_sizes, int n_in,
                              void* d_out, int out_size, void* d_ws, size_t ws_size,
                              hipStream_t stream) {
    const float* x  = (const float*)d_in[0];
    const int*   ei = (const int*)d_in[1];  // [2,E]: src row then dst row
    const float* W  = (const float*)d_in[2];
    const float* b  = (const float*)d_in[3];
    float* out = (float*)d_out;

    int n = in_sizes[0] / 64;
    int e = in_sizes[1] / 2;
    int nbuck = (n + BNODES - 1) / BNODES;  // 782 for n=100k (<=1024 for scan)

    // workspace (256B aligned): gcnt | boff | gcur | dis | grec  (~7 MB)
    auto align = [](size_t v) { return (v + 255) & ~(size_t)255; };
    char* p = (char*)d_ws;
    int* gcnt = (int*)p;          p += align((size_t)nbuck * 4);
    int* boff = (int*)p;          p += align((size_t)(nbuck + 1) * 4);
    int* gcur = (int*)p;          p += align((size_t)nbuck * 4);
    float* dis = (float*)p;       p += align((size_t)n * 4);
    unsigned int* grec = (unsigned int*)p;

    size_t lds_hist = (size_t)nbuck * 4;
    size_t lds_scatter = (size_t)nbuck * 8;
    int hist_blocks = (e + 4095) / 4096;  // ~391

    zero_int_kernel<<<(nbuck + 255) / 256, 256, 0, stream>>>(gcnt, nbuck);
    coarse_hist_kernel<<<hist_blocks, 256, lds_hist, stream>>>(ei + e, gcnt, e, nbuck);
    scan_kernel<<<1, 1024, 0, stream>>>(gcnt, nbuck, boff, gcur, e);
    binned_scatter_kernel<<<(e + EPB - 1) / EPB, 256, lds_scatter, stream>>>(ei, gcur, grec, e, nbuck);
    bucket_dis_kernel<<<nbuck, 256, 0, stream>>>(grec, boff, dis, n);
    bucket_agg_kernel<<<nbuck, 256, 0, stream>>>(x, grec, boff, dis, out, n);
    gemm_kernel<<<(n + 63) / 64, 256, 0, stream>>>(out, W, b, out, n);
}

// Round 5
// 229.715 us; speedup vs baseline: 3.9411x; 3.9411x over previous
//
#include <hip/hip_runtime.h>

// GCN layer: out = (D^-1/2 (A+I) D^-1/2) X W^T + b
// N=100000, E=1600000, D=64.
//
// Round 5: revert to the round-3 structure (CSR build + register gather,
// 223us) after round-4's LDS-tile experiment collapsed parallelism
// (782 blocks / ~3100 waves, 512-long serial dependent chains -> 748us at
// 3% VALU, 4% HBM). TLP is the resource for latency-bound gathers.
// Changes vs round 3:
//   - binned_scatter EPB 8192->2048 (196 -> 782 blocks; was leaving 3/4 of
//     CUs idle; LDS 54KB -> 18KB)
//   - gather reads bf16 x-rows (128B instead of 256B): x converted once with
//     RN; self-loop term stays fp32. Round-3 gather was ~half HBM-bound
//     (FETCH 195MB @ 3.5TB/s), so halving gathered bytes cuts its floor.
//     Runtime-guarded on ws_size; falls back to fp32 gather.
//
// Pipeline:
//   A: coarse hist over NBUCK=ceil(n/128) dst-buckets
//   B: scan bucket counts -> boff, gcur (+ off[n]=E sentinel)
//   C: binned scatter: rec=(src<<7|dst_low) into bucket regions (block-owned
//      ranges -> no cross-XCD line sharing)
//   D: per-bucket sort -> CSR srcs + off + dis=rsqrt(deg+1)
//   E: to_bf16 (optional)
//   F: gather: wave per node, 4 edges/iter, coalesced row reads
//   G: gemm: in-place tiled fp32 GEMM (tmp aliases d_out)

#define BSHIFT 7
#define BNODES 128  // nodes per bucket

__global__ void zero_int_kernel(int* __restrict__ p, int n) {
    int i = blockIdx.x * blockDim.x + threadIdx.x;
    if (i < n) p[i] = 0;
}

// --- Phase A: coarse histogram over dst >> 7 ---
__global__ __launch_bounds__(256) void coarse_hist_kernel(const int* __restrict__ dst,
                                                          int* __restrict__ gcnt,
                                                          int e, int nbuck) {
    extern __shared__ int lh[];
    for (int i = threadIdx.x; i < nbuck; i += 256) lh[i] = 0;
    __syncthreads();
    int stride = gridDim.x * 256;
    for (int i = blockIdx.x * 256 + threadIdx.x; i < e; i += stride)
        atomicAdd(&lh[dst[i] >> BSHIFT], 1);
    __syncthreads();
    for (int i = threadIdx.x; i < nbuck; i += 256) {
        int c = lh[i];
        if (c) atomicAdd(&gcnt[i], c);
    }
}

// --- Phase B: single-block scan of bucket counts (nbuck <= 1024) ---
__global__ void scan_kernel(const int* __restrict__ gcnt, int nbuck,
                            int* __restrict__ boff, int* __restrict__ gcur,
                            int e, int* __restrict__ off, int n) {
    __shared__ int sm[1024];
    int t = threadIdx.x;
    int v = (t < nbuck) ? gcnt[t] : 0;
    sm[t] = v;
    __syncthreads();
    for (int o = 1; o < 1024; o <<= 1) {
        int add = (t >= o) ? sm[t - o] : 0;
        __syncthreads();
        sm[t] += add;
        __syncthreads();
    }
    if (t < nbuck) {
        int ex = sm[t] - v;
        boff[t] = ex;
        gcur[t] = ex;
    }
    if (t == 0) {
        boff[nbuck] = e;
        off[n] = e;  // CSR sentinel
    }
}

// --- Phase C: binned scatter of packed edge records into bucket regions ---
#define EPB 2048  // edges per block -> 782 blocks (~3/CU); LDS ~18KB
__global__ __launch_bounds__(256) void binned_scatter_kernel(const int* __restrict__ ei,
                                                             int* __restrict__ gcur,
                                                             unsigned int* __restrict__ grec,
                                                             int e, int nbuck) {
    __shared__ unsigned int lrec[EPB];
    __shared__ unsigned short lbk[EPB];
    extern __shared__ int dyn[];
    int* lh = dyn;            // [nbuck] hist, then cursor
    int* lbase = dyn + nbuck; // [nbuck]
    int t = threadIdx.x;
    for (int i = t; i < nbuck; i += 256) lh[i] = 0;
    __syncthreads();
    int e0 = blockIdx.x * EPB;
    for (int i = t; i < EPB; i += 256) {
        int g = e0 + i;
        if (g >= e) break;
        int s = ei[g];
        int d = ei[e + g];
        int b = d >> BSHIFT;
        lrec[i] = ((unsigned int)s << BSHIFT) | (unsigned int)(d & (BNODES - 1));
        lbk[i] = (unsigned short)b;
        atomicAdd(&lh[b], 1);
    }
    __syncthreads();
    for (int b = t; b < nbuck; b += 256) {
        int c = lh[b];
        lbase[b] = c ? atomicAdd(&gcur[b], c) : 0;
        lh[b] = 0;  // reuse as local cursor
    }
    __syncthreads();
    for (int i = t; i < EPB; i += 256) {
        int g = e0 + i;
        if (g >= e) break;
        int b = lbk[i];
        int pos = lbase[b] + atomicAdd(&lh[b], 1);
        grec[pos] = lrec[i];
    }
}

// --- Phase D: per-bucket fine sort -> CSR srcs + off + dis ---
__global__ __launch_bounds__(256) void bucket_csr_kernel(const unsigned int* __restrict__ grec,
                                                         const int* __restrict__ boff,
                                                         int* __restrict__ srcs,
                                                         int* __restrict__ off,
                                                         float* __restrict__ dis, int n) {
    __shared__ int lh[BNODES];   // hist, then cursor
    __shared__ int ls[BNODES];   // scan
    int t = threadIdx.x;
    int b = blockIdx.x;
    int beg = boff[b];
    int end = boff[b + 1];
    int node0 = b << BSHIFT;
    if (t < BNODES) lh[t] = 0;
    __syncthreads();
    for (int i = beg + t; i < end; i += 256)
        atomicAdd(&lh[grec[i] & (BNODES - 1)], 1);
    __syncthreads();
    int c = (t < BNODES) ? lh[t] : 0;
    if (t < BNODES) ls[t] = c;
    __syncthreads();
    for (int o = 1; o < BNODES; o <<= 1) {
        int add = (t < BNODES && t >= o) ? ls[t - o] : 0;
        __syncthreads();
        if (t < BNODES) ls[t] += add;
        __syncthreads();
    }
    int ex = (t < BNODES) ? (ls[t] - c) : 0;  // exclusive
    if (t < BNODES) {
        int node = node0 + t;
        if (node < n) {
            off[node] = beg + ex;
            dis[node] = rsqrtf((float)(c + 1));  // +1 self loop
        }
        ls[t] = ex;   // keep exclusive offsets
        lh[t] = 0;    // cursor
    }
    __syncthreads();
    for (int i = beg + t; i < end; i += 256) {
        unsigned int r = grec[i];
        int nd = r & (BNODES - 1);
        int pos = beg + ls[nd] + atomicAdd(&lh[nd], 1);
        srcs[pos] = (int)(r >> BSHIFT);
    }
}

// --- Phase E: x -> bf16 (round-to-nearest) ---
__device__ inline unsigned short f2b_rn(float f) {
    unsigned u = __float_as_uint(f);
    unsigned r = u + 0x7FFFu + ((u >> 16) & 1u);
    return (unsigned short)(r >> 16);
}
__device__ inline float b2f(unsigned short h) {
    return __uint_as_float(((unsigned)h) << 16);
}

__global__ __launch_bounds__(256) void to_bf16_kernel(const float4* __restrict__ xv,
                                                      ushort4* __restrict__ xh, int nq) {
    int i = blockIdx.x * 256 + threadIdx.x;
    if (i >= nq) return;
    float4 v = xv[i];
    ushort4 o;
    o.x = f2b_rn(v.x); o.y = f2b_rn(v.y); o.z = f2b_rn(v.z); o.w = f2b_rn(v.w);
    xh[i] = o;
}

// --- Gather (bf16 rows): one wave per node, lane = feature-quad, 4 edges/iter ---
__global__ __launch_bounds__(256) void gather_bf16_kernel(const float4* __restrict__ xv,
                                                          const ushort4* __restrict__ xh,
                                                          const int* __restrict__ srcs,
                                                          const int* __restrict__ off,
                                                          const float* __restrict__ dis,
                                                          float4* __restrict__ tmpv, int n) {
    int wid = (blockIdx.x * 256 + threadIdx.x) >> 6;
    int lane = threadIdx.x & 63;
    if (wid >= n) return;
    int grp = lane >> 4;   // which of 4 concurrent edges
    int fq = lane & 15;    // feature quad
    int beg = off[wid];
    int end = off[wid + 1];
    float dn = dis[wid];
    float4 acc = {0.f, 0.f, 0.f, 0.f};
    if (grp == 0) {  // self loop: exact fp32 x
        float4 v = xv[(size_t)wid * 16 + fq];
        acc.x = v.x * dn; acc.y = v.y * dn; acc.z = v.z * dn; acc.w = v.w * dn;
    }
    for (int c = beg; c < end; c += 64) {
        int k = end - c;
        if (k > 64) k = 64;
        int sidx = 0;
        float dv = 0.f;
        if (lane < k) {
            sidx = srcs[c + lane];
            dv = dis[sidx];
        }
        for (int j = 0; j < k; j += 4) {
            int jj = j + grp;
            int s = __shfl(sidx, jj);
            float w = __shfl(dv, jj);   // lanes >= k carry w=0 -> harmless
            ushort4 h = xh[(size_t)s * 16 + fq];  // 16 lanes x 8B = 128B row
            acc.x += b2f(h.x) * w;
            acc.y += b2f(h.y) * w;
            acc.z += b2f(h.z) * w;
            acc.w += b2f(h.w) * w;
        }
    }
    for (int m = 16; m < 64; m <<= 1) {
        acc.x += __shfl_xor(acc.x, m);
        acc.y += __shfl_xor(acc.y, m);
        acc.z += __shfl_xor(acc.z, m);
        acc.w += __shfl_xor(acc.w, m);
    }
    if (lane < 16) {
        float4 o;
        o.x = acc.x * dn; o.y = acc.y * dn; o.z = acc.z * dn; o.w = acc.w * dn;
        tmpv[(size_t)wid * 16 + lane] = o;
    }
}

// --- Gather (fp32 fallback, round-3 verified) ---
__global__ __launch_bounds__(256) void gather_f32_kernel(const float4* __restrict__ xv,
                                                         const int* __restrict__ srcs,
                                                         const int* __restrict__ off,
                                                         const float* __restrict__ dis,
                                                         float4* __restrict__ tmpv, int n) {
    int wid = (blockIdx.x * 256 + threadIdx.x) >> 6;
    int lane = threadIdx.x & 63;
    if (wid >= n) return;
    int grp = lane >> 4;
    int fq = lane & 15;
    int beg = off[wid];
    int end = off[wid + 1];
    float dn = dis[wid];
    float4 acc = {0.f, 0.f, 0.f, 0.f};
    if (grp == 0) {
        float4 v = xv[(size_t)wid * 16 + fq];
        acc.x = v.x * dn; acc.y = v.y * dn; acc.z = v.z * dn; acc.w = v.w * dn;
    }
    for (int c = beg; c < end; c += 64) {
        int k = end - c;
        if (k > 64) k = 64;
        int sidx = 0;
        float dv = 0.f;
        if (lane < k) {
            sidx = srcs[c + lane];
            dv = dis[sidx];
        }
        for (int j = 0; j < k; j += 4) {
            int jj = j + grp;
            int s = __shfl(sidx, jj);
            float w = __shfl(dv, jj);
            float4 v = xv[(size_t)s * 16 + fq];
            acc.x += v.x * w; acc.y += v.y * w; acc.z += v.z * w; acc.w += v.w * w;
        }
    }
    for (int m = 16; m < 64; m <<= 1) {
        acc.x += __shfl_xor(acc.x, m);
        acc.y += __shfl_xor(acc.y, m);
        acc.z += __shfl_xor(acc.z, m);
        acc.w += __shfl_xor(acc.w, m);
    }
    if (lane < 16) {
        float4 o;
        o.x = acc.x * dn; o.y = acc.y * dn; o.z = acc.z * dn; o.w = acc.w * dn;
        tmpv[(size_t)wid * 16 + lane] = o;
    }
}

// --- In-place GEMM: out[m,o] = b[o] + sum_k A[m,k]*W[o,k]; A aliases out ---
__global__ __launch_bounds__(256) void gemm_kernel(const float* A,
                                                   const float* __restrict__ W,
                                                   const float* __restrict__ b,
                                                   float* out, int n) {
    __shared__ float At[64 * 68];
    __shared__ float Wt[64 * 64];
    int t = threadIdx.x;
    int m0 = blockIdx.x * 64;

#pragma unroll
    for (int j = 0; j < 16; ++j) {
        int idx = t + j * 256;
        int o = idx >> 6, k = idx & 63;
        Wt[k * 64 + o] = W[idx];
    }
#pragma unroll
    for (int j = 0; j < 16; ++j) {
        int idx = t + j * 256;
        int m = idx >> 6, k = idx & 63;
        int gm = m0 + m;
        At[k * 68 + m] = (gm < n) ? A[(size_t)gm * 64 + k] : 0.f;
    }
    __syncthreads();

    int tx = t & 15, ty = t >> 4;
    float acc[4][4];
#pragma unroll
    for (int i = 0; i < 4; ++i)
#pragma unroll
        for (int j = 0; j < 4; ++j) acc[i][j] = 0.f;

#pragma unroll 8
    for (int k = 0; k < 64; ++k) {
        float4 a = *(const float4*)&At[k * 68 + ty * 4];
        float4 w = *(const float4*)&Wt[k * 64 + tx * 4];
        float av[4] = {a.x, a.y, a.z, a.w};
        float wv[4] = {w.x, w.y, w.z, w.w};
#pragma unroll
        for (int i = 0; i < 4; ++i)
#pragma unroll
            for (int j = 0; j < 4; ++j) acc[i][j] += av[i] * wv[j];
    }

    float4 bb = ((const float4*)b)[tx];
    float bv[4] = {bb.x, bb.y, bb.z, bb.w};
#pragma unroll
    for (int i = 0; i < 4; ++i) {
        int gm = m0 + ty * 4 + i;
        if (gm < n) {
            float4 o;
            o.x = acc[i][0] + bv[0];
            o.y = acc[i][1] + bv[1];
            o.z = acc[i][2] + bv[2];
            o.w = acc[i][3] + bv[3];
            ((float4*)out)[(size_t)gm * 16 + tx] = o;
        }
    }
}

extern "C" void kernel_launch(void* const* d_in, const int* in_sizes, int n_in,
                              void* d_out, int out_size, void* d_ws, size_t ws_size,
                              hipStream_t stream) {
    const float* x  = (const float*)d_in[0];
    const int*   ei = (const int*)d_in[1];  // [2,E]: src row then dst row
    const float* W  = (const float*)d_in[2];
    const float* b  = (const float*)d_in[3];
    float* out = (float*)d_out;

    int n = in_sizes[0] / 64;
    int e = in_sizes[1] / 2;
    int nbuck = (n + BNODES - 1) / BNODES;  // 782 for n=100k (<=1024 for scan)

    // workspace (256B aligned): gcnt | boff | gcur | off | dis | grec | srcs | xh
    auto align = [](size_t v) { return (v + 255) & ~(size_t)255; };
    char* p = (char*)d_ws;
    int* gcnt = (int*)p;          p += align((size_t)nbuck * 4);
    int* boff = (int*)p;          p += align((size_t)(nbuck + 1) * 4);
    int* gcur = (int*)p;          p += align((size_t)nbuck * 4);
    int* off  = (int*)p;          p += align((size_t)(n + 1) * 4);
    float* dis = (float*)p;       p += align((size_t)n * 4);
    unsigned int* grec = (unsigned int*)p;  p += align((size_t)e * 4);
    int* srcs = (int*)p;          p += align((size_t)e * 4);
    ushort4* xh = (ushort4*)p;    p += align((size_t)n * 64 * 2);
    bool use_bf16 = ((size_t)(p - (char*)d_ws) <= ws_size);

    size_t lds_hist = (size_t)nbuck * 4;
    size_t lds_scatter = (size_t)nbuck * 8;
    int hist_blocks = (e + 4095) / 4096;  // ~391

    zero_int_kernel<<<(nbuck + 255) / 256, 256, 0, stream>>>(gcnt, nbuck);
    coarse_hist_kernel<<<hist_blocks, 256, lds_hist, stream>>>(ei + e, gcnt, e, nbuck);
    scan_kernel<<<1, 1024, 0, stream>>>(gcnt, nbuck, boff, gcur, e, off, n);
    binned_scatter_kernel<<<(e + EPB - 1) / EPB, 256, lds_scatter, stream>>>(ei, gcur, grec, e, nbuck);
    bucket_csr_kernel<<<nbuck, 256, 0, stream>>>(grec, boff, srcs, off, dis, n);
    if (use_bf16) {
        to_bf16_kernel<<<(n * 16 + 255) / 256, 256, 0, stream>>>((const float4*)x, xh, n * 16);
        gather_bf16_kernel<<<(n + 3) / 4, 256, 0, stream>>>((const float4*)x, xh, srcs, off,
                                                            dis, (float4*)out, n);
    } else {
        gather_f32_kernel<<<(n + 3) / 4, 256, 0, stream>>>((const float4*)x, srcs, off,
                                                           dis, (float4*)out, n);
    }
    gemm_kernel<<<(n + 63) / 64, 256, 0, stream>>>(out, W, b, out, n);
}

// Round 6
// 200.441 us; speedup vs baseline: 4.5167x; 1.1460x over previous
//
#include <hip/hip_runtime.h>

// GCN layer: out = (D^-1/2 (A+I) D^-1/2) X W^T + b
// N=100000, E=1600000, D=64.
//
// Round 6: restructure to 5 dispatches (was 8). Round-5 showed gather at
// 51us but total 230us: ~180us hidden in 7 small build/gemm dispatches.
//   1) Commute the linear: S(XW^T)+b = (SX)W^T+b. GEMM runs FIRST on dense
//      X, emits y=XW^T as bf16 in its epilogue (kills the to_bf16 dispatch
//      and the old gemm's 25MB tmp re-read). Bias added in gather epilogue.
//   2) Fixed-capacity buckets (CAP=3072 = 1.5x Poisson mean 2046; overflow
//      P~1e-90, clamped): bucket base = b*CAP, so coarse_hist + scan + zero
//      kernels all disappear; one hipMemsetAsync zeroes cursors.
//   3) bucket_csr stages its bucket in LDS and sorts IN PLACE in grec
//      (block-owned region), emitting offb/offe/dis. No srcs array.
//   4) binned_scatter EPB=4096 (391 blocks): 42B per-(block,bucket) chunks
//      vs round-5's 10B (which shared each 64B line across ~6 blocks).
//
// Pipeline:
//   memset gcur=0
//   gemm_xw:        y[n,64] = x @ W^T   (bf16 out, tiled fp32 compute)
//   binned_scatter: grec[b*CAP + cursor] = (src<<7 | dst&127)
//   bucket_csr:     LDS hist/scan/sort -> grec holds src ids grouped by dst;
//                   offb/offe[node], dis=rsqrt(deg+1)
//   gather:         out[i] = dis_i * (y_i*dis_i + sum_e y_src*dis_src) + bias

#define BSHIFT 7
#define BNODES 128
#define CAP 3072   // records per bucket region
#define EPB 4096   // edges per scatter block

__device__ inline unsigned short f2b_rn(float f) {
    unsigned u = __float_as_uint(f);
    unsigned r = u + 0x7FFFu + ((u >> 16) & 1u);
    return (unsigned short)(r >> 16);
}
__device__ inline float b2f(unsigned short h) {
    return __uint_as_float(((unsigned)h) << 16);
}

// --- GEMM: y = x @ W^T, bf16 output, no bias ---
__global__ __launch_bounds__(256) void gemm_xw_kernel(const float* __restrict__ A,
                                                      const float* __restrict__ W,
                                                      ushort4* __restrict__ yh, int n) {
    __shared__ float At[64 * 68];  // k-major, stride 68: conflict-free b128
    __shared__ float Wt[64 * 64];  // Wt[k*64+o] = W[o*64+k]
    int t = threadIdx.x;
    int m0 = blockIdx.x * 64;

#pragma unroll
    for (int j = 0; j < 16; ++j) {
        int idx = t + j * 256;
        int o = idx >> 6, k = idx & 63;
        Wt[k * 64 + o] = W[idx];
    }
#pragma unroll
    for (int j = 0; j < 16; ++j) {
        int idx = t + j * 256;
        int m = idx >> 6, k = idx & 63;
        int gm = m0 + m;
        At[k * 68 + m] = (gm < n) ? A[(size_t)gm * 64 + k] : 0.f;
    }
    __syncthreads();

    int tx = t & 15, ty = t >> 4;  // tx: output quad, ty: node quad
    float acc[4][4];
#pragma unroll
    for (int i = 0; i < 4; ++i)
#pragma unroll
        for (int j = 0; j < 4; ++j) acc[i][j] = 0.f;

#pragma unroll 8
    for (int k = 0; k < 64; ++k) {
        float4 a = *(const float4*)&At[k * 68 + ty * 4];
        float4 w = *(const float4*)&Wt[k * 64 + tx * 4];
        float av[4] = {a.x, a.y, a.z, a.w};
        float wv[4] = {w.x, w.y, w.z, w.w};
#pragma unroll
        for (int i = 0; i < 4; ++i)
#pragma unroll
            for (int j = 0; j < 4; ++j) acc[i][j] += av[i] * wv[j];
    }

#pragma unroll
    for (int i = 0; i < 4; ++i) {
        int gm = m0 + ty * 4 + i;
        if (gm < n) {
            ushort4 h;
            h.x = f2b_rn(acc[i][0]);
            h.y = f2b_rn(acc[i][1]);
            h.z = f2b_rn(acc[i][2]);
            h.w = f2b_rn(acc[i][3]);
            yh[(size_t)gm * 16 + tx] = h;
        }
    }
}

// --- binned scatter into fixed-capacity bucket regions ---
__global__ __launch_bounds__(256) void binned_scatter_kernel(const int* __restrict__ ei,
                                                             int* __restrict__ gcur,
                                                             unsigned int* __restrict__ grec,
                                                             int e, int nbuck) {
    __shared__ unsigned int lrec[EPB];   // 16 KB
    __shared__ unsigned short lbk[EPB];  // 8 KB
    extern __shared__ int dyn[];
    int* lh = dyn;            // [nbuck] hist, then cursor
    int* lbase = dyn + nbuck; // [nbuck]
    int t = threadIdx.x;
    for (int i = t; i < nbuck; i += 256) lh[i] = 0;
    __syncthreads();
    int e0 = blockIdx.x * EPB;
    int m = e - e0;
    if (m > EPB) m = EPB;
    for (int i = t; i < m; i += 256) {
        int g = e0 + i;
        int s = ei[g];
        int d = ei[e + g];
        int b = d >> BSHIFT;
        lrec[i] = ((unsigned int)s << BSHIFT) | (unsigned int)(d & (BNODES - 1));
        lbk[i] = (unsigned short)b;
        atomicAdd(&lh[b], 1);
    }
    __syncthreads();
    for (int b = t; b < nbuck; b += 256) {
        int c = lh[b];
        lbase[b] = c ? atomicAdd(&gcur[b], c) : 0;
        lh[b] = 0;  // reuse as local cursor
    }
    __syncthreads();
    for (int i = t; i < m; i += 256) {
        int b = lbk[i];
        int pos = lbase[b] + atomicAdd(&lh[b], 1);
        if (pos < CAP)  // safety clamp; P(overflow) ~ 0 for uniform dsts
            grec[(size_t)b * CAP + pos] = lrec[i];
    }
}

// --- per-bucket in-place sort: grec region -> src ids grouped by dst ---
__global__ __launch_bounds__(256) void bucket_csr_kernel(unsigned int* __restrict__ grec,
                                                         const int* __restrict__ gcur,
                                                         int* __restrict__ offb,
                                                         int* __restrict__ offe,
                                                         float* __restrict__ dis, int n) {
    __shared__ unsigned int recs[CAP];  // 12 KB staging
    __shared__ int lh[BNODES];          // hist, then cursor
    __shared__ int ls[BNODES];          // scan
    int t = threadIdx.x;
    int b = blockIdx.x;
    size_t base = (size_t)b * CAP;
    int cnt = gcur[b];
    if (cnt > CAP) cnt = CAP;
    int node0 = b << BSHIFT;

    if (t < BNODES) lh[t] = 0;
    __syncthreads();
    for (int i = t; i < cnt; i += 256) {
        unsigned int r = grec[base + i];
        recs[i] = r;
        atomicAdd(&lh[r & (BNODES - 1)], 1);
    }
    __syncthreads();
    int c = (t < BNODES) ? lh[t] : 0;
    if (t < BNODES) ls[t] = c;
    __syncthreads();
    for (int o = 1; o < BNODES; o <<= 1) {
        int add = (t < BNODES && t >= o) ? ls[t - o] : 0;
        __syncthreads();
        if (t < BNODES) ls[t] += add;
        __syncthreads();
    }
    int ex = (t < BNODES) ? (ls[t] - c) : 0;  // exclusive prefix
    if (t < BNODES) {
        int node = node0 + t;
        if (node < n) {
            offb[node] = (int)base + ex;
            offe[node] = (int)base + ex + c;
            dis[node] = rsqrtf((float)(c + 1));  // +1 self loop
        }
        ls[t] = ex;  // keep exclusive offsets
        lh[t] = 0;   // cursor
    }
    __syncthreads();
    for (int i = t; i < cnt; i += 256) {
        unsigned int r = recs[i];
        int nd = r & (BNODES - 1);
        int pos = ls[nd] + atomicAdd(&lh[nd], 1);
        grec[base + pos] = r >> BSHIFT;  // store src id only
    }
}

// --- gather over bf16 y-rows; adds bias in epilogue ---
__global__ __launch_bounds__(256) void gather_kernel(const ushort4* __restrict__ yh,
                                                     const unsigned int* __restrict__ srcs,
                                                     const int* __restrict__ offb,
                                                     const int* __restrict__ offe,
                                                     const float* __restrict__ dis,
                                                     const float* __restrict__ bias,
                                                     float4* __restrict__ out, int n) {
    int wid = (blockIdx.x * 256 + threadIdx.x) >> 6;
    int lane = threadIdx.x & 63;
    if (wid >= n) return;
    int grp = lane >> 4;   // which of 4 concurrent edges
    int fq = lane & 15;    // feature quad
    int beg = offb[wid];
    int end = offe[wid];
    float dn = dis[wid];
    float4 acc = {0.f, 0.f, 0.f, 0.f};
    if (grp == 0) {  // self loop: y[wid]*dn (scaled by dn again at the end)
        ushort4 h = yh[(size_t)wid * 16 + fq];
        acc.x = b2f(h.x) * dn; acc.y = b2f(h.y) * dn;
        acc.z = b2f(h.z) * dn; acc.w = b2f(h.w) * dn;
    }
    for (int c = beg; c < end; c += 64) {
        int k = end - c;
        if (k > 64) k = 64;
        int sidx = 0;
        float dv = 0.f;
        if (lane < k) {
            sidx = (int)srcs[c + lane];
            dv = dis[sidx];
        }
        for (int j = 0; j < k; j += 4) {
            int jj = j + grp;
            int s = __shfl(sidx, jj);
            float w = __shfl(dv, jj);   // lanes >= k carry w=0 -> harmless
            ushort4 h = yh[(size_t)s * 16 + fq];  // 16 lanes x 8B = 128B row
            acc.x += b2f(h.x) * w;
            acc.y += b2f(h.y) * w;
            acc.z += b2f(h.z) * w;
            acc.w += b2f(h.w) * w;
        }
    }
    for (int m = 16; m < 64; m <<= 1) {
        acc.x += __shfl_xor(acc.x, m);
        acc.y += __shfl_xor(acc.y, m);
        acc.z += __shfl_xor(acc.z, m);
        acc.w += __shfl_xor(acc.w, m);
    }
    if (lane < 16) {
        float4 bb = ((const float4*)bias)[fq];
        float4 o;
        o.x = acc.x * dn + bb.x;
        o.y = acc.y * dn + bb.y;
        o.z = acc.z * dn + bb.z;
        o.w = acc.w * dn + bb.w;
        out[(size_t)wid * 16 + lane] = o;
    }
}

extern "C" void kernel_launch(void* const* d_in, const int* in_sizes, int n_in,
                              void* d_out, int out_size, void* d_ws, size_t ws_size,
                              hipStream_t stream) {
    const float* x    = (const float*)d_in[0];
    const int*   ei   = (const int*)d_in[1];  // [2,E]: src row then dst row
    const float* W    = (const float*)d_in[2];
    const float* bias = (const float*)d_in[3];
    float* out = (float*)d_out;

    int n = in_sizes[0] / 64;
    int e = in_sizes[1] / 2;
    int nbuck = (n + BNODES - 1) / BNODES;  // 782 for n=100k

    // workspace (256B aligned): gcur | offb | offe | dis | grec | yh  (~23.7 MB)
    auto align = [](size_t v) { return (v + 255) & ~(size_t)255; };
    char* p = (char*)d_ws;
    int* gcur = (int*)p;          p += align((size_t)nbuck * 4);
    int* offb = (int*)p;          p += align((size_t)n * 4);
    int* offe = (int*)p;          p += align((size_t)n * 4);
    float* dis = (float*)p;       p += align((size_t)n * 4);
    unsigned int* grec = (unsigned int*)p;  p += align((size_t)nbuck * CAP * 4);
    ushort4* yh = (ushort4*)p;

    size_t lds_scatter = (size_t)nbuck * 8;

    hipMemsetAsync(gcur, 0, (size_t)nbuck * 4, stream);
    gemm_xw_kernel<<<(n + 63) / 64, 256, 0, stream>>>(x, W, yh, n);
    binned_scatter_kernel<<<(e + EPB - 1) / EPB, 256, lds_scatter, stream>>>(ei, gcur, grec, e, nbuck);
    bucket_csr_kernel<<<nbuck, 256, 0, stream>>>(grec, gcur, offb, offe, dis, n);
    gather_kernel<<<(n + 3) / 4, 256, 0, stream>>>(yh, grec, offb, offe, dis, bias,
                                                   (float4*)out, n);
}

// Round 7
// 191.078 us; speedup vs baseline: 4.7381x; 1.0490x over previous
//
#include <hip/hip_runtime.h>

// GCN layer: out = (D^-1/2 (A+I) D^-1/2) X W^T + b
// N=100000, E=1600000, D=64.
//
// Round 7: overlap + barrier surgery. Round-6 = 200us with gather 54us and
// ~146us spread over gemm/scatter/csr/memset/gaps.
//   1) Fat-fuse gemm_xw + binned_scatter into ONE dispatch (independent
//      work; gemm is VALU-bound, scatter is memory/atomic-bound -> they
//      co-schedule, m114). blockIdx<sblocks -> scatter, else gemm.
//   2) bucket_csr: replace 128-step Hillis-Steele (256 __syncthreads/block,
//      ~20us chip-wide) with wave __shfl_up scan (6 steps, 3 barriers).
//   3) gather unchanged (54us, FETCH 91.6MB >> 12.8MB y: random 128B rows
//      miss L2 persistently -> near the random-access floor).
//
// Pipeline: memset gcur; fused(gemm_xw || binned_scatter); bucket_csr; gather.

#define BSHIFT 7
#define BNODES 128
#define CAP 3072   // records per bucket region (mean 2046, P(overflow)~1e-90)
#define EPB 4096   // edges per scatter block
#define SMEM_BYTES 33792  // max(gemm 33792, scatter 24576+nbuck*8)

__device__ inline unsigned short f2b_rn(float f) {
    unsigned u = __float_as_uint(f);
    unsigned r = u + 0x7FFFu + ((u >> 16) & 1u);
    return (unsigned short)(r >> 16);
}
__device__ inline float b2f(unsigned short h) {
    return __uint_as_float(((unsigned)h) << 16);
}

// --- fused: blocks [0,sblocks) scatter edges; blocks [sblocks,...) gemm ---
__global__ __launch_bounds__(256) void fused_gemm_scatter_kernel(
    const float* __restrict__ x, const float* __restrict__ W, ushort4* __restrict__ yh,
    const int* __restrict__ ei, int* __restrict__ gcur, unsigned int* __restrict__ grec,
    int n, int e, int nbuck, int sblocks) {
    __shared__ __align__(16) unsigned char smem[SMEM_BYTES];
    int t = threadIdx.x;

    if ((int)blockIdx.x < sblocks) {
        // ---- binned scatter into fixed-capacity bucket regions ----
        unsigned int* lrec = (unsigned int*)smem;               // EPB*4 = 16384
        unsigned short* lbk = (unsigned short*)(smem + 16384);  // EPB*2 = 8192
        int* lh = (int*)(smem + 24576);                         // [nbuck]
        int* lbase = lh + nbuck;                                // [nbuck]
        for (int i = t; i < nbuck; i += 256) lh[i] = 0;
        __syncthreads();
        int e0 = blockIdx.x * EPB;
        int m = e - e0;
        if (m > EPB) m = EPB;
        for (int i = t; i < m; i += 256) {
            int g = e0 + i;
            int s = ei[g];
            int d = ei[e + g];
            int b = d >> BSHIFT;
            lrec[i] = ((unsigned int)s << BSHIFT) | (unsigned int)(d & (BNODES - 1));
            lbk[i] = (unsigned short)b;
            atomicAdd(&lh[b], 1);
        }
        __syncthreads();
        for (int b = t; b < nbuck; b += 256) {
            int c = lh[b];
            lbase[b] = c ? atomicAdd(&gcur[b], c) : 0;
            lh[b] = 0;  // reuse as local cursor
        }
        __syncthreads();
        for (int i = t; i < m; i += 256) {
            int b = lbk[i];
            int pos = lbase[b] + atomicAdd(&lh[b], 1);
            if (pos < CAP)
                grec[(size_t)b * CAP + pos] = lrec[i];
        }
    } else {
        // ---- gemm: y = x @ W^T, bf16 out ----
        float* At = (float*)smem;            // 64*68*4 = 17408, k-major stride 68
        float* Wt = (float*)(smem + 17408);  // 64*64*4 = 16384
        int m0 = ((int)blockIdx.x - sblocks) * 64;

#pragma unroll
        for (int j = 0; j < 16; ++j) {
            int idx = t + j * 256;
            int o = idx >> 6, k = idx & 63;
            Wt[k * 64 + o] = W[idx];
        }
#pragma unroll
        for (int j = 0; j < 16; ++j) {
            int idx = t + j * 256;
            int mm = idx >> 6, k = idx & 63;
            int gm = m0 + mm;
            At[k * 68 + mm] = (gm < n) ? x[(size_t)gm * 64 + k] : 0.f;
        }
        __syncthreads();

        int tx = t & 15, ty = t >> 4;
        float acc[4][4];
#pragma unroll
        for (int i = 0; i < 4; ++i)
#pragma unroll
            for (int j = 0; j < 4; ++j) acc[i][j] = 0.f;

#pragma unroll 8
        for (int k = 0; k < 64; ++k) {
            float4 a = *(const float4*)&At[k * 68 + ty * 4];
            float4 w = *(const float4*)&Wt[k * 64 + tx * 4];
            float av[4] = {a.x, a.y, a.z, a.w};
            float wv[4] = {w.x, w.y, w.z, w.w};
#pragma unroll
            for (int i = 0; i < 4; ++i)
#pragma unroll
                for (int j = 0; j < 4; ++j) acc[i][j] += av[i] * wv[j];
        }

#pragma unroll
        for (int i = 0; i < 4; ++i) {
            int gm = m0 + ty * 4 + i;
            if (gm < n) {
                ushort4 h;
                h.x = f2b_rn(acc[i][0]);
                h.y = f2b_rn(acc[i][1]);
                h.z = f2b_rn(acc[i][2]);
                h.w = f2b_rn(acc[i][3]);
                yh[(size_t)gm * 16 + tx] = h;
            }
        }
    }
}

// --- per-bucket in-place sort: grec region -> src ids grouped by dst ---
__global__ __launch_bounds__(256) void bucket_csr_kernel(unsigned int* __restrict__ grec,
                                                         const int* __restrict__ gcur,
                                                         int* __restrict__ offb,
                                                         int* __restrict__ offe,
                                                         float* __restrict__ dis, int n) {
    __shared__ unsigned int recs[CAP];  // 12 KB staging
    __shared__ int lh[BNODES];          // hist, then cursor
    __shared__ int ls[BNODES];          // exclusive offsets
    __shared__ int wtot;                // wave-0 scan total
    int t = threadIdx.x;
    int lane = t & 63;
    int b = blockIdx.x;
    size_t base = (size_t)b * CAP;
    int cnt = gcur[b];
    if (cnt > CAP) cnt = CAP;
    int node0 = b << BSHIFT;

    if (t < BNODES) lh[t] = 0;
    __syncthreads();
    for (int i = t; i < cnt; i += 256) {
        unsigned int r = grec[base + i];
        recs[i] = r;
        atomicAdd(&lh[r & (BNODES - 1)], 1);
    }
    __syncthreads();
    int c = (t < BNODES) ? lh[t] : 0;
    // inclusive shfl scan over 128 bins (waves 0 and 1), 6 steps + 1 fixup
    int v = c;
#pragma unroll
    for (int o = 1; o < 64; o <<= 1) {
        int u = __shfl_up(v, o, 64);
        if (lane >= o) v += u;
    }
    if (t == 63) wtot = v;
    __syncthreads();
    if (t >= 64 && t < BNODES) v += wtot;
    int ex = v - c;  // exclusive prefix
    if (t < BNODES) {
        int node = node0 + t;
        if (node < n) {
            offb[node] = (int)base + ex;
            offe[node] = (int)base + ex + c;
            dis[node] = rsqrtf((float)(c + 1));  // +1 self loop
        }
        ls[t] = ex;
        lh[t] = 0;  // cursor
    }
    __syncthreads();
    for (int i = t; i < cnt; i += 256) {
        unsigned int r = recs[i];
        int nd = r & (BNODES - 1);
        int pos = ls[nd] + atomicAdd(&lh[nd], 1);
        grec[base + pos] = r >> BSHIFT;  // store src id only
    }
}

// --- gather over bf16 y-rows; adds bias in epilogue ---
__global__ __launch_bounds__(256) void gather_kernel(const ushort4* __restrict__ yh,
                                                     const unsigned int* __restrict__ srcs,
                                                     const int* __restrict__ offb,
                                                     const int* __restrict__ offe,
                                                     const float* __restrict__ dis,
                                                     const float* __restrict__ bias,
                                                     float4* __restrict__ out, int n) {
    int wid = (blockIdx.x * 256 + threadIdx.x) >> 6;
    int lane = threadIdx.x & 63;
    if (wid >= n) return;
    int grp = lane >> 4;   // which of 4 concurrent edges
    int fq = lane & 15;    // feature quad
    int beg = offb[wid];
    int end = offe[wid];
    float dn = dis[wid];
    float4 acc = {0.f, 0.f, 0.f, 0.f};
    if (grp == 0) {  // self loop: y[wid]*dn (scaled by dn again at the end)
        ushort4 h = yh[(size_t)wid * 16 + fq];
        acc.x = b2f(h.x) * dn; acc.y = b2f(h.y) * dn;
        acc.z = b2f(h.z) * dn; acc.w = b2f(h.w) * dn;
    }
    for (int c = beg; c < end; c += 64) {
        int k = end - c;
        if (k > 64) k = 64;
        int sidx = 0;
        float dv = 0.f;
        if (lane < k) {
            sidx = (int)srcs[c + lane];
            dv = dis[sidx];
        }
        for (int j = 0; j < k; j += 4) {
            int jj = j + grp;
            int s = __shfl(sidx, jj);
            float w = __shfl(dv, jj);   // lanes >= k carry w=0 -> harmless
            ushort4 h = yh[(size_t)s * 16 + fq];  // 16 lanes x 8B = 128B row
            acc.x += b2f(h.x) * w;
            acc.y += b2f(h.y) * w;
            acc.z += b2f(h.z) * w;
            acc.w += b2f(h.w) * w;
        }
    }
    for (int m = 16; m < 64; m <<= 1) {
        acc.x += __shfl_xor(acc.x, m);
        acc.y += __shfl_xor(acc.y, m);
        acc.z += __shfl_xor(acc.z, m);
        acc.w += __shfl_xor(acc.w, m);
    }
    if (lane < 16) {
        float4 bb = ((const float4*)bias)[fq];
        float4 o;
        o.x = acc.x * dn + bb.x;
        o.y = acc.y * dn + bb.y;
        o.z = acc.z * dn + bb.z;
        o.w = acc.w * dn + bb.w;
        out[(size_t)wid * 16 + lane] = o;
    }
}

extern "C" void kernel_launch(void* const* d_in, const int* in_sizes, int n_in,
                              void* d_out, int out_size, void* d_ws, size_t ws_size,
                              hipStream_t stream) {
    const float* x    = (const float*)d_in[0];
    const int*   ei   = (const int*)d_in[1];  // [2,E]: src row then dst row
    const float* W    = (const float*)d_in[2];
    const float* bias = (const float*)d_in[3];
    float* out = (float*)d_out;

    int n = in_sizes[0] / 64;
    int e = in_sizes[1] / 2;
    int nbuck = (n + BNODES - 1) / BNODES;  // 782; must be <= 1152 for smem layout

    // workspace (256B aligned): gcur | offb | offe | dis | grec | yh  (~23.7 MB)
    auto align = [](size_t v) { return (v + 255) & ~(size_t)255; };
    char* p = (char*)d_ws;
    int* gcur = (int*)p;          p += align((size_t)nbuck * 4);
    int* offb = (int*)p;          p += align((size_t)n * 4);
    int* offe = (int*)p;          p += align((size_t)n * 4);
    float* dis = (float*)p;       p += align((size_t)n * 4);
    unsigned int* grec = (unsigned int*)p;  p += align((size_t)nbuck * CAP * 4);
    ushort4* yh = (ushort4*)p;

    int sblocks = (e + EPB - 1) / EPB;   // 391
    int gblocks = (n + 63) / 64;         // 1563

    hipMemsetAsync(gcur, 0, (size_t)nbuck * 4, stream);
    fused_gemm_scatter_kernel<<<sblocks + gblocks, 256, 0, stream>>>(
        x, W, yh, ei, gcur, grec, n, e, nbuck, sblocks);
    bucket_csr_kernel<<<nbuck, 256, 0, stream>>>(grec, gcur, offb, offe, dis, n);
    gather_kernel<<<(n + 3) / 4, 256, 0, stream>>>(yh, grec, offb, offe, dis, bias,
                                                   (float4*)out, n);
}